// Round 1
// baseline (643.094 us; speedup 1.0000x reference)
//
#include <hip/hip_runtime.h>
#include <hip/hip_bf16.h>

// Action_Prediction: 3-layer MLP (relu) -> scalar logit -> per-segment softmax
// -> Gumbel-max sample. N=524288, B=4096 segments of 128 contiguous nodes.
//
// R3: (1) operand-swap MFMA: weights = A-operand, activations = B-operand, so
// D = [feature][node]. C-layout rows (4 consecutive regs) are now consecutive
// FEATURES -> inter-layer writeback is vectorized ushort4 (was 128 scalar
// ds_write_u16/thread). (2) 512-thread blocks (8 waves), same 128-row tile:
// LDS still 2 blocks/CU but 16 waves/CU (was 8) -> 4 waves/SIMD latency
// hiding. (3) SEGSZ == block tile (128), so softmax+Gumbel sampling is fused
// into the block epilogue: sample_kernel and the 2MB logits round-trip die.
//
// d_ws layout: W0t bf16 [n=256][k=128]; W1t [256][256]; W2t [256][256]
// (n-major so weight A-frags are contiguous 16B).

#define NFULL 524288
#define BSEG  4096
#define SEGSZ 128
#define DIN   128
#define HID   256
#define MROWS 128
#define KPAD  264   // LDS row stride (bf16): rotates banks, keeps 16B align

typedef __bf16 bf16x8 __attribute__((ext_vector_type(8)));
typedef float  f32x4  __attribute__((ext_vector_type(4)));

__device__ __forceinline__ unsigned short f2bf(float f) {
  __hip_bfloat16 h = __float2bfloat16(f);
  return __builtin_bit_cast(unsigned short, h);
}

// ------------------------------------------------- weight transpose+convert
__global__ __launch_bounds__(256) void convert_weights(
    const float* __restrict__ W0, const float* __restrict__ W1,
    const float* __restrict__ W2,
    unsigned short* __restrict__ W0t, unsigned short* __restrict__ W1t,
    unsigned short* __restrict__ W2t) {
  const int tid = blockIdx.x * 256 + threadIdx.x;
  if (tid < 32768) {                     // W0 [k=128][n=256] -> W0t[n][k]
    const int n = tid >> 7, k = tid & 127;
    W0t[tid] = f2bf(W0[k * 256 + n]);
  } else if (tid < 98304) {              // W1 [256][256]
    const int u = tid - 32768;
    const int n = u >> 8, k = u & 255;
    W1t[u] = f2bf(W1[k * 256 + n]);
  } else if (tid < 163840) {             // W2 [256][256]
    const int u = tid - 98304;
    const int n = u >> 8, k = u & 255;
    W2t[u] = f2bf(W2[k * 256 + n]);
  }
}

// ---------------------------------------------------------------- layer core
// MFMA 16x16x32, A = weights Wt[n][k] (M dim = out-features), B = activations
// Abuf[node][k] (N dim = nodes). Wave (wm,wn) owns features [wm*64,+64) x
// nodes [wn*64,+64): acc[4 mt][4 nt]. A-frag: A[m=lane&15][k=(lane>>4)*8+j]
// -> Wt row (wm*64+mt*16+l15), contiguous k. B-frag: B[k][n=lane&15] ->
// Abuf row (wn*64+nt*16+l15), contiguous k (ds_read_b128). C/D: col=lane&15
// (node), row=(lane>>4)*4+reg (feature)  (guide §3, m89/m91-verified).

template<int K>
__device__ __forceinline__ void do_layer(
    const unsigned short* Abuf, const unsigned short* __restrict__ Wt,
    const float* __restrict__ bias, int wm, int wn, int lane,
    f32x4 (&acc)[4][4]) {
  const int l15 = lane & 15;
  const int q   = lane >> 4;
  #pragma unroll
  for (int mt = 0; mt < 4; ++mt) {
    f32x4 c;
    #pragma unroll
    for (int r = 0; r < 4; ++r) c[r] = bias[wm * 64 + mt * 16 + q * 4 + r];
    #pragma unroll
    for (int nt = 0; nt < 4; ++nt) acc[mt][nt] = c;
  }
  const unsigned short* Wb = Wt + (size_t)(wm * 64 + l15) * K + q * 8;
  const unsigned short* Ab = Abuf + (wn * 64 + l15) * KPAD + q * 8;
  for (int k0 = 0; k0 < K; k0 += 32) {
    bf16x8 a[4];
    #pragma unroll
    for (int mt = 0; mt < 4; ++mt)
      a[mt] = *(const bf16x8*)(Wb + mt * 16 * K + k0);
    #pragma unroll
    for (int nt = 0; nt < 4; ++nt) {
      const bf16x8 b = *(const bf16x8*)(Ab + nt * 16 * KPAD + k0);
      #pragma unroll
      for (int mt = 0; mt < 4; ++mt)
        acc[mt][nt] = __builtin_amdgcn_mfma_f32_16x16x32_bf16(
            a[mt], b, acc[mt][nt], 0, 0, 0);
    }
  }
}

// writeback: lane holds 4 consecutive features (q*4+r) at fixed node ->
// one ushort4 per (mt,nt). 16 ds_write_b64/thread (was 128 ds_write_u16).
__device__ __forceinline__ void writeback_relu(
    unsigned short* Abuf, int wm, int wn, int lane, const f32x4 (&acc)[4][4]) {
  const int l15 = lane & 15, q = lane >> 4;
  #pragma unroll
  for (int nt = 0; nt < 4; ++nt) {
    const int node = wn * 64 + nt * 16 + l15;
    #pragma unroll
    for (int mt = 0; mt < 4; ++mt) {
      const int feat = wm * 64 + mt * 16 + q * 4;
      ushort4 p;
      p.x = f2bf(fmaxf(acc[mt][nt][0], 0.f));
      p.y = f2bf(fmaxf(acc[mt][nt][1], 0.f));
      p.z = f2bf(fmaxf(acc[mt][nt][2], 0.f));
      p.w = f2bf(fmaxf(acc[mt][nt][3], 0.f));
      *(ushort4*)&Abuf[node * KPAD + feat] = p;
    }
  }
}

// ------------------------------------------------------------------ sampling
__device__ __forceinline__ void threefry2x32_42(unsigned x0, unsigned x1,
                                                unsigned& o0, unsigned& o1) {
  const unsigned ks0 = 0u, ks1 = 42u;
  const unsigned ks2 = ks0 ^ ks1 ^ 0x1BD11BDAu;
  x0 += ks0; x1 += ks1;
#define TF_R(r) { x0 += x1; x1 = (x1 << (r)) | (x1 >> (32 - (r))); x1 ^= x0; }
  TF_R(13) TF_R(15) TF_R(26) TF_R(6)   x0 += ks1; x1 += ks2 + 1u;
  TF_R(17) TF_R(29) TF_R(16) TF_R(24)  x0 += ks2; x1 += ks0 + 2u;
  TF_R(13) TF_R(15) TF_R(26) TF_R(6)   x0 += ks0; x1 += ks1 + 3u;
  TF_R(17) TF_R(29) TF_R(16) TF_R(24)  x0 += ks1; x1 += ks2 + 4u;
  TF_R(13) TF_R(15) TF_R(26) TF_R(6)   x0 += ks2; x1 += ks0 + 5u;
#undef TF_R
  o0 = x0; o1 = x1;
}

// -------------------------------------------------------------- fused kernel
__global__ __launch_bounds__(512, 4) void mlp_fused(
    const float* __restrict__ X,
    const unsigned short* __restrict__ W0t,
    const unsigned short* __restrict__ W1t,
    const unsigned short* __restrict__ W2t,
    const float* __restrict__ b0, const float* __restrict__ b1,
    const float* __restrict__ b2,
    const float* __restrict__ Wf, const float* __restrict__ bfp,
    float* __restrict__ out) {
  __shared__ alignas(16) unsigned short Abuf[MROWS * KPAD];  // 66 KB
  __shared__ float WfS[HID];
  __shared__ float Lpart[4][MROWS];
  __shared__ float red2[2];
  __shared__ float smax_sh[2];
  __shared__ int   sidx_sh[2];
  __shared__ float probs_sh[SEGSZ];

  const int tid  = threadIdx.x;
  const int lane = tid & 63;
  const int w    = tid >> 6;     // 0..7
  const int wm   = w >> 1;       // 0..3 feature-group (64 feats)
  const int wn   = w & 1;        // 0..1 node-group (64 nodes)
  const int l15  = lane & 15;
  const int q    = lane >> 4;
  const size_t row0 = (size_t)blockIdx.x * MROWS;

  if (tid < HID) WfS[tid] = Wf[tid];

  // stage X (fp32 -> bf16), coalesced float4 reads, ds_write_b64
  {
    const int k4 = (tid & 31) * 4;
    int r = tid >> 5;            // 0..15
    #pragma unroll
    for (int it = 0; it < 8; ++it, r += 16) {
      const float4 v = *(const float4*)&X[(row0 + r) * DIN + k4];
      ushort4 p;
      p.x = f2bf(v.x); p.y = f2bf(v.y); p.z = f2bf(v.z); p.w = f2bf(v.w);
      *(ushort4*)&Abuf[r * KPAD + k4] = p;
    }
  }
  __syncthreads();

  f32x4 acc[4][4];
  do_layer<DIN>(Abuf, W0t, b0, wm, wn, lane, acc);   // h0
  __syncthreads();
  writeback_relu(Abuf, wm, wn, lane, acc);
  __syncthreads();
  do_layer<HID>(Abuf, W1t, b1, wm, wn, lane, acc);   // h1
  __syncthreads();
  writeback_relu(Abuf, wm, wn, lane, acc);
  __syncthreads();
  do_layer<HID>(Abuf, W2t, b2, wm, wn, lane, acc);   // h2 (pre-relu, in regs)

  // head: logit[node] = sum_feat relu(h2[feat][node]) * Wf[feat] + bf.
  // Lane holds feats wm*64+mt*16+q*4+r at nodes wn*64+nt*16+l15.
  #pragma unroll
  for (int nt = 0; nt < 4; ++nt) {
    float s = 0.f;
    #pragma unroll
    for (int mt = 0; mt < 4; ++mt)
      #pragma unroll
      for (int r = 0; r < 4; ++r)
        s = fmaf(fmaxf(acc[mt][nt][r], 0.f),
                 WfS[wm * 64 + mt * 16 + q * 4 + r], s);
    s += __shfl_xor(s, 16, 64);          // reduce over q
    s += __shfl_xor(s, 32, 64);
    if (q == 0) Lpart[wm][wn * 64 + nt * 16 + l15] = s;
  }
  __syncthreads();

  // fused per-segment softmax + Gumbel-max (segment == this block's 128 rows)
  float e = 0.f, prob = 0.f;
  if (tid < SEGSZ) {
    const float lg = Lpart[0][tid] + Lpart[1][tid] + Lpart[2][tid] +
                     Lpart[3][tid] + bfp[0];
    e = expf(lg);
    float v = e;
    #pragma unroll
    for (int off = 32; off >= 1; off >>= 1) v += __shfl_xor(v, off, 64);
    if ((tid & 63) == 0) red2[tid >> 6] = v;
  }
  __syncthreads();
  if (tid < SEGSZ) {
    const float S = red2[0] + red2[1];
    prob = e / S;
    probs_sh[tid] = prob;
    unsigned o0, o1;
    threefry2x32_42(0u, (unsigned)(row0 + (size_t)tid), o0, o1);
    const float f = __uint_as_float(0x3f800000u | (o0 >> 9)) - 1.0f;
    const float u = fmaxf(1e-20f, f + 1e-20f);
    const float g = -logf(-logf(u));
    float ms = logf(prob) + g;
    int   mi = (int)row0 + tid;
    #pragma unroll
    for (int off = 1; off < 64; off <<= 1) {
      const float os = __shfl_xor(ms, off, 64);
      const int   oi = __shfl_xor(mi, off, 64);
      if (os > ms || (os == ms && oi > mi)) { ms = os; mi = oi; }
    }
    if ((tid & 63) == 0) { smax_sh[tid >> 6] = ms; sidx_sh[tid >> 6] = mi; }
  }
  __syncthreads();
  if (tid == 0) {
    const float s0 = smax_sh[0], s1 = smax_sh[1];
    const int   i0 = sidx_sh[0], i1 = sidx_sh[1];
    const int win = (s1 > s0 || (s1 == s0 && i1 > i0)) ? i1 : i0;
    const int s = blockIdx.x;
    out[s]            = probs_sh[win - (int)row0];
    out[BSEG + s]     = (float)(win - (int)row0);
    out[2 * BSEG + s] = (float)win;
  }
}

extern "C" void kernel_launch(void* const* d_in, const int* in_sizes, int n_in,
                              void* d_out, int out_size, void* d_ws, size_t ws_size,
                              hipStream_t stream) {
  const float* X  = (const float*)d_in[0];
  const float* W0 = (const float*)d_in[1];
  const float* b0 = (const float*)d_in[2];
  const float* W1 = (const float*)d_in[3];
  const float* b1 = (const float*)d_in[4];
  const float* W2 = (const float*)d_in[5];
  const float* b2 = (const float*)d_in[6];
  const float* Wf = (const float*)d_in[7];
  const float* bf = (const float*)d_in[8];

  unsigned short* W0t = (unsigned short*)d_ws;
  unsigned short* W1t = W0t + 256 * 128;
  unsigned short* W2t = W1t + 256 * 256;
  float* out = (float*)d_out;

  convert_weights<<<640, 256, 0, stream>>>(W0, W1, W2, W0t, W1t, W2t);
  mlp_fused<<<BSEG, 512, 0, stream>>>(X, W0t, W1t, W2t, b0, b1, b2,
                                      Wf, bf, out);
}

// Round 2
// 627.253 us; speedup vs baseline: 1.0253x; 1.0253x over previous
//
#include <hip/hip_runtime.h>
#include <hip/hip_bf16.h>

// Action_Prediction: 3-layer MLP (relu) -> scalar logit -> per-segment softmax
// -> Gumbel-max sample. N=524288, B=4096 segments of 128 contiguous nodes.
//
// R4: fat-wave regime. R3 post-mortem: __launch_bounds__(512,4) capped the
// combined VGPR+AGPR budget at 128/wave (VGPR_Count=64) -> no room to pipeline
// the dependent global weight-frag loads -> 396 us despite 2x occupancy.
// R4 = 256 threads / 4 waves, wave owns 128 feats x 64 nodes (acc[8][4]):
//  - LDS B-frag reused 8x (was 4x): per-layer ds_read_b128 count halves.
//  - explicit 1-step weight-frag prefetch (regs available at 2 waves/SIMD).
//  - keeps R3 wins: operand-swap (D=[feat][node]) -> ushort4 writeback;
//    fused per-segment softmax+Gumbel epilogue (block tile == segment).
//
// d_ws layout: W0t bf16 [n=256][k=128]; W1t [256][256]; W2t [256][256]
// (n-major so weight A-frags are contiguous 16B).

#define NFULL 524288
#define BSEG  4096
#define SEGSZ 128
#define DIN   128
#define HID   256
#define MROWS 128
#define KPAD  264   // LDS row stride (bf16): rotates banks, keeps 16B align

typedef __bf16 bf16x8 __attribute__((ext_vector_type(8)));
typedef float  f32x4  __attribute__((ext_vector_type(4)));

__device__ __forceinline__ unsigned short f2bf(float f) {
  __hip_bfloat16 h = __float2bfloat16(f);
  return __builtin_bit_cast(unsigned short, h);
}

// ------------------------------------------------- weight transpose+convert
__global__ __launch_bounds__(256) void convert_weights(
    const float* __restrict__ W0, const float* __restrict__ W1,
    const float* __restrict__ W2,
    unsigned short* __restrict__ W0t, unsigned short* __restrict__ W1t,
    unsigned short* __restrict__ W2t) {
  const int tid = blockIdx.x * 256 + threadIdx.x;
  if (tid < 32768) {                     // W0 [k=128][n=256] -> W0t[n][k]
    const int n = tid >> 7, k = tid & 127;
    W0t[tid] = f2bf(W0[k * 256 + n]);
  } else if (tid < 98304) {              // W1 [256][256]
    const int u = tid - 32768;
    const int n = u >> 8, k = u & 255;
    W1t[u] = f2bf(W1[k * 256 + n]);
  } else if (tid < 163840) {             // W2 [256][256]
    const int u = tid - 98304;
    const int n = u >> 8, k = u & 255;
    W2t[u] = f2bf(W2[k * 256 + n]);
  }
}

// ---------------------------------------------------------------- layer core
// MFMA 16x16x32, A = weights Wt[n][k] (M = out-features), B = activations
// Abuf[node][k] (N = nodes). Wave w: wm = w>>1 (feat half, 128 feats),
// wn = w&1 (node half, 64 nodes). acc[8 mt][4 nt].
// A-frag: Wt row (wm*128+mt*16+l15), k = q*8+j (contiguous 16B).
// B-frag: Abuf row (wn*64+nt*16+l15), k contiguous (ds_read_b128).
// C/D: col=lane&15 (node), row=q*4+reg (feat)  (guide §3, m89/m91-verified).

template<int K>
__device__ __forceinline__ void do_layer(
    const unsigned short* Abuf, const unsigned short* __restrict__ Wt,
    const float* __restrict__ bias, int wm, int wn, int lane,
    f32x4 (&acc)[8][4]) {
  const int l15 = lane & 15;
  const int q   = lane >> 4;
  #pragma unroll
  for (int mt = 0; mt < 8; ++mt) {
    const float4 bv = *(const float4*)&bias[wm * 128 + mt * 16 + q * 4];
    f32x4 c; c[0] = bv.x; c[1] = bv.y; c[2] = bv.z; c[3] = bv.w;
    #pragma unroll
    for (int nt = 0; nt < 4; ++nt) acc[mt][nt] = c;
  }
  const unsigned short* Wb = Wt + (size_t)(wm * 128 + l15) * K + q * 8;
  const unsigned short* Ab = Abuf + (wn * 64 + l15) * KPAD + q * 8;

  bf16x8 a[8];
  #pragma unroll
  for (int mt = 0; mt < 8; ++mt)
    a[mt] = *(const bf16x8*)(Wb + mt * 16 * K);

  #pragma unroll
  for (int k0 = 0; k0 < K; k0 += 32) {
    bf16x8 an[8];
    if (k0 + 32 < K) {                       // prefetch next k-step's A-frags
      #pragma unroll
      for (int mt = 0; mt < 8; ++mt)
        an[mt] = *(const bf16x8*)(Wb + mt * 16 * K + k0 + 32);
    }
    #pragma unroll
    for (int nt = 0; nt < 4; ++nt) {
      const bf16x8 b = *(const bf16x8*)(Ab + nt * 16 * KPAD + k0);
      #pragma unroll
      for (int mt = 0; mt < 8; ++mt)
        acc[mt][nt] = __builtin_amdgcn_mfma_f32_16x16x32_bf16(
            a[mt], b, acc[mt][nt], 0, 0, 0);
    }
    if (k0 + 32 < K) {
      #pragma unroll
      for (int mt = 0; mt < 8; ++mt) a[mt] = an[mt];
    }
  }
}

// writeback: lane holds 4 consecutive feats (q*4+r) at fixed node ->
// one ushort4 per (mt,nt): 32 ds_write_b64/thread, no scalar u16 writes.
__device__ __forceinline__ void writeback_relu(
    unsigned short* Abuf, int wm, int wn, int lane, const f32x4 (&acc)[8][4]) {
  const int l15 = lane & 15, q = lane >> 4;
  #pragma unroll
  for (int nt = 0; nt < 4; ++nt) {
    const int node = wn * 64 + nt * 16 + l15;
    #pragma unroll
    for (int mt = 0; mt < 8; ++mt) {
      const int feat = wm * 128 + mt * 16 + q * 4;
      ushort4 p;
      p.x = f2bf(fmaxf(acc[mt][nt][0], 0.f));
      p.y = f2bf(fmaxf(acc[mt][nt][1], 0.f));
      p.z = f2bf(fmaxf(acc[mt][nt][2], 0.f));
      p.w = f2bf(fmaxf(acc[mt][nt][3], 0.f));
      *(ushort4*)&Abuf[node * KPAD + feat] = p;
    }
  }
}

// ------------------------------------------------------------------ sampling
__device__ __forceinline__ void threefry2x32_42(unsigned x0, unsigned x1,
                                                unsigned& o0, unsigned& o1) {
  const unsigned ks0 = 0u, ks1 = 42u;
  const unsigned ks2 = ks0 ^ ks1 ^ 0x1BD11BDAu;
  x0 += ks0; x1 += ks1;
#define TF_R(r) { x0 += x1; x1 = (x1 << (r)) | (x1 >> (32 - (r))); x1 ^= x0; }
  TF_R(13) TF_R(15) TF_R(26) TF_R(6)   x0 += ks1; x1 += ks2 + 1u;
  TF_R(17) TF_R(29) TF_R(16) TF_R(24)  x0 += ks2; x1 += ks0 + 2u;
  TF_R(13) TF_R(15) TF_R(26) TF_R(6)   x0 += ks0; x1 += ks1 + 3u;
  TF_R(17) TF_R(29) TF_R(16) TF_R(24)  x0 += ks1; x1 += ks2 + 4u;
  TF_R(13) TF_R(15) TF_R(26) TF_R(6)   x0 += ks2; x1 += ks0 + 5u;
#undef TF_R
  o0 = x0; o1 = x1;
}

// -------------------------------------------------------------- fused kernel
__global__ __launch_bounds__(256, 2) void mlp_fused(
    const float* __restrict__ X,
    const unsigned short* __restrict__ W0t,
    const unsigned short* __restrict__ W1t,
    const unsigned short* __restrict__ W2t,
    const float* __restrict__ b0, const float* __restrict__ b1,
    const float* __restrict__ b2,
    const float* __restrict__ Wf, const float* __restrict__ bfp,
    float* __restrict__ out) {
  __shared__ alignas(16) unsigned short Abuf[MROWS * KPAD];  // 66 KB
  __shared__ float WfS[HID];
  __shared__ float Lpart[2][MROWS];
  __shared__ float red2[2];
  __shared__ float smax_sh[2];
  __shared__ int   sidx_sh[2];
  __shared__ float probs_sh[SEGSZ];

  const int tid  = threadIdx.x;
  const int lane = tid & 63;
  const int w    = tid >> 6;     // 0..3
  const int wm   = w >> 1;       // 0..1 feature-half (128 feats)
  const int wn   = w & 1;        // 0..1 node-half (64 nodes)
  const int l15  = lane & 15;
  const int q    = lane >> 4;
  const size_t row0 = (size_t)blockIdx.x * MROWS;

  if (tid < HID) WfS[tid] = Wf[tid];

  // stage X (fp32 -> bf16), coalesced float4 reads, ds_write_b64
  {
    const int k4 = (tid & 31) * 4;
    int r = tid >> 5;            // 0..7
    #pragma unroll
    for (int it = 0; it < 16; ++it, r += 8) {
      const float4 v = *(const float4*)&X[(row0 + r) * DIN + k4];
      ushort4 p;
      p.x = f2bf(v.x); p.y = f2bf(v.y); p.z = f2bf(v.z); p.w = f2bf(v.w);
      *(ushort4*)&Abuf[r * KPAD + k4] = p;
    }
  }
  __syncthreads();

  f32x4 acc[8][4];
  do_layer<DIN>(Abuf, W0t, b0, wm, wn, lane, acc);   // h0
  __syncthreads();
  writeback_relu(Abuf, wm, wn, lane, acc);
  __syncthreads();
  do_layer<HID>(Abuf, W1t, b1, wm, wn, lane, acc);   // h1
  __syncthreads();
  writeback_relu(Abuf, wm, wn, lane, acc);
  __syncthreads();
  do_layer<HID>(Abuf, W2t, b2, wm, wn, lane, acc);   // h2 (pre-relu, in regs)

  // head: logit[node] = sum_feat relu(h2[feat][node]) * Wf[feat] + bf.
  // Lane holds feats wm*128+mt*16+q*4+r at nodes wn*64+nt*16+l15.
  #pragma unroll
  for (int nt = 0; nt < 4; ++nt) {
    float s = 0.f;
    #pragma unroll
    for (int mt = 0; mt < 8; ++mt)
      #pragma unroll
      for (int r = 0; r < 4; ++r)
        s = fmaf(fmaxf(acc[mt][nt][r], 0.f),
                 WfS[wm * 128 + mt * 16 + q * 4 + r], s);
    s += __shfl_xor(s, 16, 64);          // reduce over q
    s += __shfl_xor(s, 32, 64);
    if (q == 0) Lpart[wm][wn * 64 + nt * 16 + l15] = s;
  }
  __syncthreads();

  // fused per-segment softmax + Gumbel-max (segment == this block's 128 rows)
  float e = 0.f, prob = 0.f;
  if (tid < SEGSZ) {
    const float lg = Lpart[0][tid] + Lpart[1][tid] + bfp[0];
    e = expf(lg);
    float v = e;
    #pragma unroll
    for (int off = 32; off >= 1; off >>= 1) v += __shfl_xor(v, off, 64);
    if ((tid & 63) == 0) red2[tid >> 6] = v;
  }
  __syncthreads();
  if (tid < SEGSZ) {
    const float S = red2[0] + red2[1];
    prob = e / S;
    probs_sh[tid] = prob;
    unsigned o0, o1;
    threefry2x32_42(0u, (unsigned)(row0 + (size_t)tid), o0, o1);
    const float f = __uint_as_float(0x3f800000u | (o0 >> 9)) - 1.0f;
    const float u = fmaxf(1e-20f, f + 1e-20f);
    const float g = -logf(-logf(u));
    float ms = logf(prob) + g;
    int   mi = (int)row0 + tid;
    #pragma unroll
    for (int off = 1; off < 64; off <<= 1) {
      const float os = __shfl_xor(ms, off, 64);
      const int   oi = __shfl_xor(mi, off, 64);
      if (os > ms || (os == ms && oi > mi)) { ms = os; mi = oi; }
    }
    if ((tid & 63) == 0) { smax_sh[tid >> 6] = ms; sidx_sh[tid >> 6] = mi; }
  }
  __syncthreads();
  if (tid == 0) {
    const float s0 = smax_sh[0], s1 = smax_sh[1];
    const int   i0 = sidx_sh[0], i1 = sidx_sh[1];
    const int win = (s1 > s0 || (s1 == s0 && i1 > i0)) ? i1 : i0;
    const int s = blockIdx.x;
    out[s]            = probs_sh[win - (int)row0];
    out[BSEG + s]     = (float)(win - (int)row0);
    out[2 * BSEG + s] = (float)win;
  }
}

extern "C" void kernel_launch(void* const* d_in, const int* in_sizes, int n_in,
                              void* d_out, int out_size, void* d_ws, size_t ws_size,
                              hipStream_t stream) {
  const float* X  = (const float*)d_in[0];
  const float* W0 = (const float*)d_in[1];
  const float* b0 = (const float*)d_in[2];
  const float* W1 = (const float*)d_in[3];
  const float* b1 = (const float*)d_in[4];
  const float* W2 = (const float*)d_in[5];
  const float* b2 = (const float*)d_in[6];
  const float* Wf = (const float*)d_in[7];
  const float* bf = (const float*)d_in[8];

  unsigned short* W0t = (unsigned short*)d_ws;
  unsigned short* W1t = W0t + 256 * 128;
  unsigned short* W2t = W1t + 256 * 256;
  float* out = (float*)d_out;

  convert_weights<<<640, 256, 0, stream>>>(W0, W1, W2, W0t, W1t, W2t);
  mlp_fused<<<BSEG, 256, 0, stream>>>(X, W0t, W1t, W2t, b0, b1, b2,
                                      Wf, bf, out);
}

// Round 3
// 525.653 us; speedup vs baseline: 1.2234x; 1.1933x over previous
//
#include <hip/hip_runtime.h>
#include <hip/hip_bf16.h>

// Action_Prediction: 3-layer MLP (relu) -> scalar logit -> per-segment softmax
// -> Gumbel-max sample. N=524288, B=4096 segments of 128 contiguous nodes.
//
// R5: R2's memory topology + R3/R4's verified wins.
// Post-mortem R4: wave tile 128feat x 64node doubled per-block global weight
// traffic (2 waves read the same feat panel) and halved cheap LDS reads ->
// MfmaUtil 19%, 377us (worse than R2's 280us with 4 distinct panels).
// R5 wave tile = 64 feats x 128 nodes (wm=w, 4 distinct panels, acc[4][8]):
//   - per k-step: 4 global weight frags (prefetched) + 8 LDS b128 = R2 shape
//   - D=[feat][node] kept -> writeback stays vectorized ushort4
//   - fused per-segment softmax+Gumbel epilogue kept (no logits round-trip)
//
// d_ws layout: W0t bf16 [n=256][k=128]; W1t [256][256]; W2t [256][256]
// (n-major so weight A-frags are contiguous 16B).

#define NFULL 524288
#define BSEG  4096
#define SEGSZ 128
#define DIN   128
#define HID   256
#define MROWS 128
#define KPAD  264   // LDS row stride (bf16): rotates banks, keeps 16B align

typedef __bf16 bf16x8 __attribute__((ext_vector_type(8)));
typedef float  f32x4  __attribute__((ext_vector_type(4)));

__device__ __forceinline__ unsigned short f2bf(float f) {
  __hip_bfloat16 h = __float2bfloat16(f);
  return __builtin_bit_cast(unsigned short, h);
}

// ------------------------------------------------- weight transpose+convert
__global__ __launch_bounds__(256) void convert_weights(
    const float* __restrict__ W0, const float* __restrict__ W1,
    const float* __restrict__ W2,
    unsigned short* __restrict__ W0t, unsigned short* __restrict__ W1t,
    unsigned short* __restrict__ W2t) {
  const int tid = blockIdx.x * 256 + threadIdx.x;
  if (tid < 32768) {                     // W0 [k=128][n=256] -> W0t[n][k]
    const int n = tid >> 7, k = tid & 127;
    W0t[tid] = f2bf(W0[k * 256 + n]);
  } else if (tid < 98304) {              // W1 [256][256]
    const int u = tid - 32768;
    const int n = u >> 8, k = u & 255;
    W1t[u] = f2bf(W1[k * 256 + n]);
  } else if (tid < 163840) {             // W2 [256][256]
    const int u = tid - 98304;
    const int n = u >> 8, k = u & 255;
    W2t[u] = f2bf(W2[k * 256 + n]);
  }
}

// ---------------------------------------------------------------- layer core
// MFMA 16x16x32, A = weights Wt[n][k] (M = out-features), B = activations
// Abuf[node][k] (N = nodes). Wave w = wm owns feats [wm*64,+64) x ALL 128
// nodes: acc[4 mt][8 nt]. Per k-step: 4 global A-frags (distinct panel per
// wave, 1-step prefetch) + 8 LDS B-frags (ds_read_b128, each reused 4x).
// A-frag: Wt row (wm*64+mt*16+l15), k=q*8+j contiguous 16B.
// B-frag: Abuf row (nt*16+l15), k contiguous.
// C/D: col=lane&15 (node), row=q*4+reg (feat)  (guide §3, m89/m91-verified).

template<int K>
__device__ __forceinline__ void do_layer(
    const unsigned short* Abuf, const unsigned short* __restrict__ Wt,
    const float* __restrict__ bias, int wm, int lane,
    f32x4 (&acc)[4][8]) {
  const int l15 = lane & 15;
  const int q   = lane >> 4;
  #pragma unroll
  for (int mt = 0; mt < 4; ++mt) {
    const float4 bv = *(const float4*)&bias[wm * 64 + mt * 16 + q * 4];
    f32x4 c; c[0] = bv.x; c[1] = bv.y; c[2] = bv.z; c[3] = bv.w;
    #pragma unroll
    for (int nt = 0; nt < 8; ++nt) acc[mt][nt] = c;
  }
  const unsigned short* Wb = Wt + (size_t)(wm * 64 + l15) * K + q * 8;
  const unsigned short* Ab = Abuf + l15 * KPAD + q * 8;

  bf16x8 a[4];
  #pragma unroll
  for (int mt = 0; mt < 4; ++mt)
    a[mt] = *(const bf16x8*)(Wb + mt * 16 * K);

  #pragma unroll
  for (int k0 = 0; k0 < K; k0 += 32) {
    bf16x8 an[4];
    if (k0 + 32 < K) {                       // prefetch next k-step's A-frags
      #pragma unroll
      for (int mt = 0; mt < 4; ++mt)
        an[mt] = *(const bf16x8*)(Wb + mt * 16 * K + k0 + 32);
    }
    #pragma unroll
    for (int nt = 0; nt < 8; ++nt) {
      const bf16x8 b = *(const bf16x8*)(Ab + nt * 16 * KPAD + k0);
      #pragma unroll
      for (int mt = 0; mt < 4; ++mt)
        acc[mt][nt] = __builtin_amdgcn_mfma_f32_16x16x32_bf16(
            a[mt], b, acc[mt][nt], 0, 0, 0);
    }
    if (k0 + 32 < K) {
      #pragma unroll
      for (int mt = 0; mt < 4; ++mt) a[mt] = an[mt];
    }
  }
}

// writeback: lane holds 4 consecutive feats (q*4+r) at fixed node ->
// one ushort4 per (mt,nt): 32 ds_write_b64/thread, no scalar u16 writes.
__device__ __forceinline__ void writeback_relu(
    unsigned short* Abuf, int wm, int lane, const f32x4 (&acc)[4][8]) {
  const int l15 = lane & 15, q = lane >> 4;
  #pragma unroll
  for (int nt = 0; nt < 8; ++nt) {
    const int node = nt * 16 + l15;
    #pragma unroll
    for (int mt = 0; mt < 4; ++mt) {
      const int feat = wm * 64 + mt * 16 + q * 4;
      ushort4 p;
      p.x = f2bf(fmaxf(acc[mt][nt][0], 0.f));
      p.y = f2bf(fmaxf(acc[mt][nt][1], 0.f));
      p.z = f2bf(fmaxf(acc[mt][nt][2], 0.f));
      p.w = f2bf(fmaxf(acc[mt][nt][3], 0.f));
      *(ushort4*)&Abuf[node * KPAD + feat] = p;
    }
  }
}

// ------------------------------------------------------------------ sampling
__device__ __forceinline__ void threefry2x32_42(unsigned x0, unsigned x1,
                                                unsigned& o0, unsigned& o1) {
  const unsigned ks0 = 0u, ks1 = 42u;
  const unsigned ks2 = ks0 ^ ks1 ^ 0x1BD11BDAu;
  x0 += ks0; x1 += ks1;
#define TF_R(r) { x0 += x1; x1 = (x1 << (r)) | (x1 >> (32 - (r))); x1 ^= x0; }
  TF_R(13) TF_R(15) TF_R(26) TF_R(6)   x0 += ks1; x1 += ks2 + 1u;
  TF_R(17) TF_R(29) TF_R(16) TF_R(24)  x0 += ks2; x1 += ks0 + 2u;
  TF_R(13) TF_R(15) TF_R(26) TF_R(6)   x0 += ks0; x1 += ks1 + 3u;
  TF_R(17) TF_R(29) TF_R(16) TF_R(24)  x0 += ks1; x1 += ks2 + 4u;
  TF_R(13) TF_R(15) TF_R(26) TF_R(6)   x0 += ks2; x1 += ks0 + 5u;
#undef TF_R
  o0 = x0; o1 = x1;
}

// -------------------------------------------------------------- fused kernel
__global__ __launch_bounds__(256, 2) void mlp_fused(
    const float* __restrict__ X,
    const unsigned short* __restrict__ W0t,
    const unsigned short* __restrict__ W1t,
    const unsigned short* __restrict__ W2t,
    const float* __restrict__ b0, const float* __restrict__ b1,
    const float* __restrict__ b2,
    const float* __restrict__ Wf, const float* __restrict__ bfp,
    float* __restrict__ out) {
  __shared__ alignas(16) unsigned short Abuf[MROWS * KPAD];  // 66 KB
  __shared__ float WfS[HID];
  __shared__ float Lpart[4][MROWS];
  __shared__ float red2[2];
  __shared__ float smax_sh[2];
  __shared__ int   sidx_sh[2];
  __shared__ float probs_sh[SEGSZ];

  const int tid  = threadIdx.x;
  const int lane = tid & 63;
  const int wm   = tid >> 6;     // 0..3: feature group (64 feats), all nodes
  const int l15  = lane & 15;
  const int q    = lane >> 4;
  const size_t row0 = (size_t)blockIdx.x * MROWS;

  if (tid < HID) WfS[tid] = Wf[tid];

  // stage X (fp32 -> bf16), coalesced float4 reads, ds_write_b64
  {
    const int k4 = (tid & 31) * 4;
    int r = tid >> 5;            // 0..7
    #pragma unroll
    for (int it = 0; it < 16; ++it, r += 8) {
      const float4 v = *(const float4*)&X[(row0 + r) * DIN + k4];
      ushort4 p;
      p.x = f2bf(v.x); p.y = f2bf(v.y); p.z = f2bf(v.z); p.w = f2bf(v.w);
      *(ushort4*)&Abuf[r * KPAD + k4] = p;
    }
  }
  __syncthreads();

  f32x4 acc[4][8];
  do_layer<DIN>(Abuf, W0t, b0, wm, lane, acc);   // h0
  __syncthreads();
  writeback_relu(Abuf, wm, lane, acc);
  __syncthreads();
  do_layer<HID>(Abuf, W1t, b1, wm, lane, acc);   // h1
  __syncthreads();
  writeback_relu(Abuf, wm, lane, acc);
  __syncthreads();
  do_layer<HID>(Abuf, W2t, b2, wm, lane, acc);   // h2 (pre-relu, in regs)

  // head: logit[node] = sum_feat relu(h2[feat][node]) * Wf[feat] + bf.
  // Lane holds feats wm*64+mt*16+q*4+r at nodes nt*16+l15.
  #pragma unroll
  for (int nt = 0; nt < 8; ++nt) {
    float s = 0.f;
    #pragma unroll
    for (int mt = 0; mt < 4; ++mt)
      #pragma unroll
      for (int r = 0; r < 4; ++r)
        s = fmaf(fmaxf(acc[mt][nt][r], 0.f),
                 WfS[wm * 64 + mt * 16 + q * 4 + r], s);
    s += __shfl_xor(s, 16, 64);          // reduce over q
    s += __shfl_xor(s, 32, 64);
    if (q == 0) Lpart[wm][nt * 16 + l15] = s;
  }
  __syncthreads();

  // fused per-segment softmax + Gumbel-max (segment == this block's 128 rows)
  float e = 0.f, prob = 0.f;
  if (tid < SEGSZ) {
    const float lg = Lpart[0][tid] + Lpart[1][tid] + Lpart[2][tid] +
                     Lpart[3][tid] + bfp[0];
    e = expf(lg);
    float v = e;
    #pragma unroll
    for (int off = 32; off >= 1; off >>= 1) v += __shfl_xor(v, off, 64);
    if ((tid & 63) == 0) red2[tid >> 6] = v;
  }
  __syncthreads();
  if (tid < SEGSZ) {
    const float S = red2[0] + red2[1];
    prob = e / S;
    probs_sh[tid] = prob;
    unsigned o0, o1;
    threefry2x32_42(0u, (unsigned)(row0 + (size_t)tid), o0, o1);
    const float f = __uint_as_float(0x3f800000u | (o0 >> 9)) - 1.0f;
    const float u = fmaxf(1e-20f, f + 1e-20f);
    const float g = -logf(-logf(u));
    float ms = logf(prob) + g;
    int   mi = (int)row0 + tid;
    #pragma unroll
    for (int off = 1; off < 64; off <<= 1) {
      const float os = __shfl_xor(ms, off, 64);
      const int   oi = __shfl_xor(mi, off, 64);
      if (os > ms || (os == ms && oi > mi)) { ms = os; mi = oi; }
    }
    if ((tid & 63) == 0) { smax_sh[tid >> 6] = ms; sidx_sh[tid >> 6] = mi; }
  }
  __syncthreads();
  if (tid == 0) {
    const float s0 = smax_sh[0], s1 = smax_sh[1];
    const int   i0 = sidx_sh[0], i1 = sidx_sh[1];
    const int win = (s1 > s0 || (s1 == s0 && i1 > i0)) ? i1 : i0;
    const int s = blockIdx.x;
    out[s]            = probs_sh[win - (int)row0];
    out[BSEG + s]     = (float)(win - (int)row0);
    out[2 * BSEG + s] = (float)win;
  }
}

extern "C" void kernel_launch(void* const* d_in, const int* in_sizes, int n_in,
                              void* d_out, int out_size, void* d_ws, size_t ws_size,
                              hipStream_t stream) {
  const float* X  = (const float*)d_in[0];
  const float* W0 = (const float*)d_in[1];
  const float* b0 = (const float*)d_in[2];
  const float* W1 = (const float*)d_in[3];
  const float* b1 = (const float*)d_in[4];
  const float* W2 = (const float*)d_in[5];
  const float* b2 = (const float*)d_in[6];
  const float* Wf = (const float*)d_in[7];
  const float* bf = (const float*)d_in[8];

  unsigned short* W0t = (unsigned short*)d_ws;
  unsigned short* W1t = W0t + 256 * 128;
  unsigned short* W2t = W1t + 256 * 256;
  float* out = (float*)d_out;

  convert_weights<<<640, 256, 0, stream>>>(W0, W1, W2, W0t, W1t, W2t);
  mlp_fused<<<BSEG, 256, 0, stream>>>(X, W0t, W1t, W2t, b0, b1, b2,
                                      Wf, bf, out);
}

// Round 4
// 521.050 us; speedup vs baseline: 1.2342x; 1.0088x over previous
//
#include <hip/hip_runtime.h>
#include <hip/hip_bf16.h>

// Action_Prediction: 3-layer MLP (relu) -> scalar logit -> per-segment softmax
// -> Gumbel-max sample. N=524288, B=4096 segments of 128 contiguous nodes.
//
// R6: R5 topology (wave = 64 feats x 128 nodes, 4 distinct weight panels,
// D=[feat][node], fused sampling) with three serialization fixes:
//  1. 32x32x16 MFMA: same memory traffic, half the MFMA instructions at a
//     ~15% higher rate (2382 vs 2075 TF ubench). acc = f32x16[2][4].
//  2. X-staging fused into L0 as a 4-chunk software pipeline: issue chunk
//     c+1 global loads -> MFMA chunk c -> cvt+ds_write c+1 -> barrier.
//     Kills the ~7k-cyc block-start stage bubble.
//  3. s_setprio(1) around pure-MFMA clusters (2 resident blocks at
//     different phases = the role-diversity regime where T5 pays).
//
// d_ws layout: W0t bf16 [n=256][k=128]; W1t [256][256]; W2t [256][256]
// (n-major so weight A-frags are contiguous 16B).

#define NFULL 524288
#define BSEG  4096
#define SEGSZ 128
#define DIN   128
#define HID   256
#define MROWS 128
#define KPAD  264   // LDS row stride (bf16): 528B = 33 granules -> bank-balanced

typedef __bf16 bf16x8 __attribute__((ext_vector_type(8)));
typedef float  f32x16 __attribute__((ext_vector_type(16)));

#define MFMA32(a, b, c) __builtin_amdgcn_mfma_f32_32x32x16_bf16((a), (b), (c), 0, 0, 0)

__device__ __forceinline__ unsigned short f2bf(float f) {
  __hip_bfloat16 h = __float2bfloat16(f);
  return __builtin_bit_cast(unsigned short, h);
}

// ------------------------------------------------- weight transpose+convert
__global__ __launch_bounds__(256) void convert_weights(
    const float* __restrict__ W0, const float* __restrict__ W1,
    const float* __restrict__ W2,
    unsigned short* __restrict__ W0t, unsigned short* __restrict__ W1t,
    unsigned short* __restrict__ W2t) {
  const int tid = blockIdx.x * 256 + threadIdx.x;
  if (tid < 32768) {                     // W0 [k=128][n=256] -> W0t[n][k]
    const int n = tid >> 7, k = tid & 127;
    W0t[tid] = f2bf(W0[k * 256 + n]);
  } else if (tid < 98304) {              // W1 [256][256]
    const int u = tid - 32768;
    const int n = u >> 8, k = u & 255;
    W1t[u] = f2bf(W1[k * 256 + n]);
  } else if (tid < 163840) {             // W2 [256][256]
    const int u = tid - 98304;
    const int n = u >> 8, k = u & 255;
    W2t[u] = f2bf(W2[k * 256 + n]);
  }
}

// ---------------------------------------------------------------- MFMA core
// 32x32x16: A-frag lane l: A[m = l&31][k = (l>>5)*8 + j] (16B contiguous k).
// B-frag lane l: B[k = (l>>5)*8 + j][n = l&31] -> Abuf row (node), contig k.
// C/D lane l, reg r: col = l&31 (node), row = (r&3) + 8*(r>>2) + 4*(l>>5)
// (feat)  [guide §3, m74/m101-verified].

__device__ __forceinline__ void init_acc(const float* __restrict__ bias,
                                         int wm, int h, f32x16 (&acc)[2][4]) {
  #pragma unroll
  for (int mt = 0; mt < 2; ++mt) {
    f32x16 c;
    #pragma unroll
    for (int g = 0; g < 4; ++g) {
      const float4 bv = *(const float4*)&bias[wm * 64 + mt * 32 + 8 * g + 4 * h];
      c[4 * g + 0] = bv.x; c[4 * g + 1] = bv.y;
      c[4 * g + 2] = bv.z; c[4 * g + 3] = bv.w;
    }
    #pragma unroll
    for (int nt = 0; nt < 4; ++nt) acc[mt][nt] = c;
  }
}

template<int K>
__device__ __forceinline__ void do_layer(
    const unsigned short* Abuf, const unsigned short* __restrict__ Wt,
    const float* __restrict__ bias, int wm, int lane, f32x16 (&acc)[2][4]) {
  const int l31 = lane & 31, h = lane >> 5;
  init_acc(bias, wm, h, acc);
  const unsigned short* Wb = Wt + (size_t)(wm * 64 + l31) * K + h * 8;
  const unsigned short* Ab = Abuf + (size_t)l31 * KPAD + h * 8;
  bf16x8 a0 = *(const bf16x8*)(Wb);
  bf16x8 a1 = *(const bf16x8*)(Wb + 32 * K);
  #pragma unroll
  for (int s = 0; s < K / 16; ++s) {
    bf16x8 an0, an1;
    if (s + 1 < K / 16) {                       // 1-step weight prefetch
      an0 = *(const bf16x8*)(Wb + (s + 1) * 16);
      an1 = *(const bf16x8*)(Wb + 32 * K + (s + 1) * 16);
    }
    bf16x8 b[4];
    #pragma unroll
    for (int nt = 0; nt < 4; ++nt)
      b[nt] = *(const bf16x8*)(Ab + nt * 32 * KPAD + s * 16);
    __builtin_amdgcn_s_setprio(1);
    #pragma unroll
    for (int nt = 0; nt < 4; ++nt) {
      acc[0][nt] = MFMA32(a0, b[nt], acc[0][nt]);
      acc[1][nt] = MFMA32(a1, b[nt], acc[1][nt]);
    }
    __builtin_amdgcn_s_setprio(0);
    if (s + 1 < K / 16) { a0 = an0; a1 = an1; }
  }
}

// L0 with fused chunked X staging. Chunk c = k in [32c, 32c+32).
// Thread t stages row (t>>1), 16 floats at k-offset (t&1)*16.
// Pipeline: load(c+1) issued before MFMA(c); cvt+write(c+1) after; barrier.
__device__ __forceinline__ void do_layer0(
    unsigned short* Abuf, const float* __restrict__ Xr,
    const unsigned short* __restrict__ Wt, const float* __restrict__ bias,
    int wm, int lane, int tid, f32x16 (&acc)[2][4]) {
  const int l31 = lane & 31, h = lane >> 5;
  const int sr = tid >> 1, sk = (tid & 1) * 16;
  const float* Xp = Xr + (size_t)sr * DIN + sk;
  unsigned short* Sp = Abuf + sr * KPAD + sk;

  float4 V[4][4];
  #pragma unroll
  for (int i = 0; i < 4; ++i) V[1][i] = *(const float4*)(Xp + 32 + i * 4);
  #pragma unroll
  for (int i = 0; i < 4; ++i) V[0][i] = *(const float4*)(Xp + i * 4);
  #pragma unroll
  for (int i = 0; i < 4; ++i) {           // store chunk 0
    ushort4 p;
    p.x = f2bf(V[0][i].x); p.y = f2bf(V[0][i].y);
    p.z = f2bf(V[0][i].z); p.w = f2bf(V[0][i].w);
    *(ushort4*)(Sp + i * 4) = p;
  }
  __syncthreads();

  init_acc(bias, wm, h, acc);
  const unsigned short* Wb = Wt + (size_t)(wm * 64 + l31) * DIN + h * 8;
  const unsigned short* Ab = Abuf + (size_t)l31 * KPAD + h * 8;
  bf16x8 a0 = *(const bf16x8*)(Wb);
  bf16x8 a1 = *(const bf16x8*)(Wb + 32 * DIN);

  #pragma unroll
  for (int s = 0; s < 8; ++s) {           // k16-step; chunk = s>>1
    bf16x8 an0, an1;
    if (s < 7) {
      an0 = *(const bf16x8*)(Wb + (s + 1) * 16);
      an1 = *(const bf16x8*)(Wb + 32 * DIN + (s + 1) * 16);
    }
    if (s == 1) {                         // issue loads chunk 2
      #pragma unroll
      for (int i = 0; i < 4; ++i) V[2][i] = *(const float4*)(Xp + 64 + i * 4);
    }
    if (s == 3) {                         // issue loads chunk 3
      #pragma unroll
      for (int i = 0; i < 4; ++i) V[3][i] = *(const float4*)(Xp + 96 + i * 4);
    }
    bf16x8 b[4];
    #pragma unroll
    for (int nt = 0; nt < 4; ++nt)
      b[nt] = *(const bf16x8*)(Ab + nt * 32 * KPAD + s * 16);
    __builtin_amdgcn_s_setprio(1);
    #pragma unroll
    for (int nt = 0; nt < 4; ++nt) {
      acc[0][nt] = MFMA32(a0, b[nt], acc[0][nt]);
      acc[1][nt] = MFMA32(a1, b[nt], acc[1][nt]);
    }
    __builtin_amdgcn_s_setprio(0);
    if (s == 1 || s == 3 || s == 5) {     // cvt+write chunk (s+1)/2 + 1... = c+1
      const int c = (s >> 1) + 1;
      #pragma unroll
      for (int i = 0; i < 4; ++i) {
        ushort4 p;
        p.x = f2bf(V[c][i].x); p.y = f2bf(V[c][i].y);
        p.z = f2bf(V[c][i].z); p.w = f2bf(V[c][i].w);
        *(ushort4*)(Sp + c * 32 + i * 4) = p;
      }
      __syncthreads();
    }
    if (s < 7) { a0 = an0; a1 = an1; }
  }
}

// writeback: lane holds 4 consecutive feats per reg-quad at fixed node ->
// ushort4 per (mt,nt,g): 32 ds_write_b64/thread.
__device__ __forceinline__ void writeback_relu(
    unsigned short* Abuf, int wm, int lane, const f32x16 (&acc)[2][4]) {
  const int l31 = lane & 31, h = lane >> 5;
  #pragma unroll
  for (int nt = 0; nt < 4; ++nt) {
    const int node = nt * 32 + l31;
    #pragma unroll
    for (int mt = 0; mt < 2; ++mt) {
      #pragma unroll
      for (int g = 0; g < 4; ++g) {
        const int feat = wm * 64 + mt * 32 + 8 * g + 4 * h;
        ushort4 p;
        p.x = f2bf(fmaxf(acc[mt][nt][4 * g + 0], 0.f));
        p.y = f2bf(fmaxf(acc[mt][nt][4 * g + 1], 0.f));
        p.z = f2bf(fmaxf(acc[mt][nt][4 * g + 2], 0.f));
        p.w = f2bf(fmaxf(acc[mt][nt][4 * g + 3], 0.f));
        *(ushort4*)&Abuf[node * KPAD + feat] = p;
      }
    }
  }
}

// ------------------------------------------------------------------ sampling
__device__ __forceinline__ void threefry2x32_42(unsigned x0, unsigned x1,
                                                unsigned& o0, unsigned& o1) {
  const unsigned ks0 = 0u, ks1 = 42u;
  const unsigned ks2 = ks0 ^ ks1 ^ 0x1BD11BDAu;
  x0 += ks0; x1 += ks1;
#define TF_R(r) { x0 += x1; x1 = (x1 << (r)) | (x1 >> (32 - (r))); x1 ^= x0; }
  TF_R(13) TF_R(15) TF_R(26) TF_R(6)   x0 += ks1; x1 += ks2 + 1u;
  TF_R(17) TF_R(29) TF_R(16) TF_R(24)  x0 += ks2; x1 += ks0 + 2u;
  TF_R(13) TF_R(15) TF_R(26) TF_R(6)   x0 += ks0; x1 += ks1 + 3u;
  TF_R(17) TF_R(29) TF_R(16) TF_R(24)  x0 += ks1; x1 += ks2 + 4u;
  TF_R(13) TF_R(15) TF_R(26) TF_R(6)   x0 += ks2; x1 += ks0 + 5u;
#undef TF_R
  o0 = x0; o1 = x1;
}

// -------------------------------------------------------------- fused kernel
__global__ __launch_bounds__(256, 2) void mlp_fused(
    const float* __restrict__ X,
    const unsigned short* __restrict__ W0t,
    const unsigned short* __restrict__ W1t,
    const unsigned short* __restrict__ W2t,
    const float* __restrict__ b0, const float* __restrict__ b1,
    const float* __restrict__ b2,
    const float* __restrict__ Wf, const float* __restrict__ bfp,
    float* __restrict__ out) {
  __shared__ alignas(16) unsigned short Abuf[MROWS * KPAD];  // 66 KB
  __shared__ float WfS[HID];
  __shared__ float Lpart[4][MROWS];
  __shared__ float red2[2];
  __shared__ float smax_sh[2];
  __shared__ int   sidx_sh[2];
  __shared__ float probs_sh[SEGSZ];

  const int tid  = threadIdx.x;
  const int lane = tid & 63;
  const int wm   = tid >> 6;     // 0..3: feature group (64 feats), all nodes
  const int l31  = lane & 31;
  const int h    = lane >> 5;
  const size_t row0 = (size_t)blockIdx.x * MROWS;

  if (tid < HID) WfS[tid] = Wf[tid];

  f32x16 acc[2][4];
  do_layer0(Abuf, X + row0 * DIN, W0t, b0, wm, lane, tid, acc);   // h0 (stage fused)
  __syncthreads();
  writeback_relu(Abuf, wm, lane, acc);
  __syncthreads();
  do_layer<HID>(Abuf, W1t, b1, wm, lane, acc);   // h1
  __syncthreads();
  writeback_relu(Abuf, wm, lane, acc);
  __syncthreads();
  do_layer<HID>(Abuf, W2t, b2, wm, lane, acc);   // h2 (pre-relu, in regs)

  // head: logit[node] = sum_feat relu(h2[feat][node]) * Wf[feat] + bf.
  // Lane holds feats wm*64+mt*32+(r&3)+8*(r>>2)+4h at nodes nt*32+l31.
  #pragma unroll
  for (int nt = 0; nt < 4; ++nt) {
    float sv = 0.f;
    #pragma unroll
    for (int mt = 0; mt < 2; ++mt)
      #pragma unroll
      for (int r = 0; r < 16; ++r)
        sv = fmaf(fmaxf(acc[mt][nt][r], 0.f),
                  WfS[wm * 64 + mt * 32 + (r & 3) + 8 * (r >> 2) + 4 * h], sv);
    sv += __shfl_xor(sv, 32, 64);          // combine the two feat-halves
    if (h == 0) Lpart[wm][nt * 32 + l31] = sv;
  }
  __syncthreads();

  // fused per-segment softmax + Gumbel-max (segment == this block's 128 rows)
  float e = 0.f, prob = 0.f;
  if (tid < SEGSZ) {
    const float lg = Lpart[0][tid] + Lpart[1][tid] + Lpart[2][tid] +
                     Lpart[3][tid] + bfp[0];
    e = expf(lg);
    float v = e;
    #pragma unroll
    for (int off = 32; off >= 1; off >>= 1) v += __shfl_xor(v, off, 64);
    if ((tid & 63) == 0) red2[tid >> 6] = v;
  }
  __syncthreads();
  if (tid < SEGSZ) {
    const float S = red2[0] + red2[1];
    prob = e / S;
    probs_sh[tid] = prob;
    unsigned o0, o1;
    threefry2x32_42(0u, (unsigned)(row0 + (size_t)tid), o0, o1);
    const float f = __uint_as_float(0x3f800000u | (o0 >> 9)) - 1.0f;
    const float u = fmaxf(1e-20f, f + 1e-20f);
    const float g = -logf(-logf(u));
    float ms = logf(prob) + g;
    int   mi = (int)row0 + tid;
    #pragma unroll
    for (int off = 1; off < 64; off <<= 1) {
      const float os = __shfl_xor(ms, off, 64);
      const int   oi = __shfl_xor(mi, off, 64);
      if (os > ms || (os == ms && oi > mi)) { ms = os; mi = oi; }
    }
    if ((tid & 63) == 0) { smax_sh[tid >> 6] = ms; sidx_sh[tid >> 6] = mi; }
  }
  __syncthreads();
  if (tid == 0) {
    const float s0 = smax_sh[0], s1 = smax_sh[1];
    const int   i0 = sidx_sh[0], i1 = sidx_sh[1];
    const int win = (s1 > s0 || (s1 == s0 && i1 > i0)) ? i1 : i0;
    const int s = blockIdx.x;
    out[s]            = probs_sh[win - (int)row0];
    out[BSEG + s]     = (float)(win - (int)row0);
    out[2 * BSEG + s] = (float)win;
  }
}

extern "C" void kernel_launch(void* const* d_in, const int* in_sizes, int n_in,
                              void* d_out, int out_size, void* d_ws, size_t ws_size,
                              hipStream_t stream) {
  const float* X  = (const float*)d_in[0];
  const float* W0 = (const float*)d_in[1];
  const float* b0 = (const float*)d_in[2];
  const float* W1 = (const float*)d_in[3];
  const float* b1 = (const float*)d_in[4];
  const float* W2 = (const float*)d_in[5];
  const float* b2 = (const float*)d_in[6];
  const float* Wf = (const float*)d_in[7];
  const float* bf = (const float*)d_in[8];

  unsigned short* W0t = (unsigned short*)d_ws;
  unsigned short* W1t = W0t + 256 * 128;
  unsigned short* W2t = W1t + 256 * 256;
  float* out = (float*)d_out;

  convert_weights<<<640, 256, 0, stream>>>(W0, W1, W2, W0t, W1t, W2t);
  mlp_fused<<<BSEG, 256, 0, stream>>>(X, W0t, W1t, W2t, b0, b1, b2,
                                      Wf, bf, out);
}